// Round 1
// baseline (1256.714 us; speedup 1.0000x reference)
//
#include <hip/hip_runtime.h>

#define BATCH   4096
#define NRULES  512
#define NNEUR   128

typedef float f32x4 __attribute__((ext_vector_type(4)));

// Kernel 1: head_t[n][b] = dot(x[n][b][:], head_w[n][:]) + head_b[n]
// One wave handles 8 consecutive rows rid = n*BATCH + b (all share n).
// Per row: lane i loads float4 at r=i*4 and r=256+i*4 (two fully-coalesced
// 1 KB wave transactions), FMAs against the matching head_w fragment,
// then a 6-step butterfly reduction. 8 rows/wave = 16 independent float4
// loads in flight per lane (16 KB/wave) for latency hiding.
// Output layout is TRANSPOSED [NNEUR][BATCH]: the 8 results land in
// head_t[n][b0..b0+7] -> one contiguous 32 B store from lanes 0..7
// (the [B][N] layout scattered 4 B stores at 512 B stride -> RMW traffic).
__global__ __launch_bounds__(256) void head_kernel(
    const float* __restrict__ x,
    const float* __restrict__ head_w,
    const float* __restrict__ head_b,
    float* __restrict__ head_t)   // [NNEUR][BATCH]
{
    const int lane = threadIdx.x & 63;
    const int wave = threadIdx.x >> 6;
    const long long wave_g = (long long)blockIdx.x * 4 + wave;
    const long long rid0 = wave_g * 8;            // first of 8 rows
    const int n  = (int)(rid0 >> 12);             // rid / BATCH
    const int b0 = (int)(rid0 & (BATCH - 1));     // rid % BATCH (8 rows share n)

    // head_w fragment for this lane (reused for all 8 rows; L2-resident)
    const f32x4* w4 = (const f32x4*)(head_w + (size_t)n * NRULES);
    const f32x4 wA = w4[lane];        // r in [lane*4, lane*4+4)
    const f32x4 wB = w4[64 + lane];   // r in [256+lane*4, ...)

    const float* xrow = x + rid0 * NRULES;
    float acc[8];
#pragma unroll
    for (int j = 0; j < 8; ++j) {
        const f32x4* xr = (const f32x4*)(xrow + (size_t)j * NRULES);
        // x is streamed exactly once: nt keeps it from evicting head_w in L2
        f32x4 a = __builtin_nontemporal_load(xr + lane);
        f32x4 b = __builtin_nontemporal_load(xr + 64 + lane);
        acc[j] = a[0]*wA[0] + a[1]*wA[1] + a[2]*wA[2] + a[3]*wA[3]
               + b[0]*wB[0] + b[1]*wB[1] + b[2]*wB[2] + b[3]*wB[3];
    }

#pragma unroll
    for (int j = 0; j < 8; ++j) {
#pragma unroll
        for (int off = 32; off > 0; off >>= 1)
            acc[j] += __shfl_xor(acc[j], off, 64);
    }

    if (lane < 8) {
        // static 8-way select (runtime-indexed acc[] would spill to scratch)
        float v = (lane == 0) ? acc[0]
                : (lane == 1) ? acc[1]
                : (lane == 2) ? acc[2]
                : (lane == 3) ? acc[3]
                : (lane == 4) ? acc[4]
                : (lane == 5) ? acc[5]
                : (lane == 6) ? acc[6]
                              : acc[7];
        v += head_b[n];
        head_t[(size_t)n * BATCH + b0 + lane] = v;   // 32 B contiguous store
    }
}

// Kernel 2: one THREAD per batch row b (no shuffles, no LDS).
// With head_t transposed, per n-iteration a wave reads 256 B contiguous;
// foot_w[n] is wave-uniform -> scalar loads. Softmax of 2 per thread,
// coalesced float2 store.
__global__ __launch_bounds__(64) void foot_kernel(
    const float* __restrict__ head_t,  // [NNEUR][BATCH]
    const float* __restrict__ foot_w,  // [2][NNEUR]
    const float* __restrict__ foot_b,  // [2]
    float* __restrict__ out)           // [BATCH][2]
{
    const int b = blockIdx.x * 64 + threadIdx.x;

    float l0 = foot_b[0];
    float l1 = foot_b[1];
#pragma unroll 16
    for (int n = 0; n < NNEUR; ++n) {
        const float h = head_t[(size_t)n * BATCH + b];
        l0 = fmaf(h, foot_w[n], l0);
        l1 = fmaf(h, foot_w[NNEUR + n], l1);
    }

    const float m  = fmaxf(l0, l1);
    const float e0 = __expf(l0 - m);
    const float e1 = __expf(l1 - m);
    const float inv = 1.0f / (e0 + e1);
    float2 r;
    r.x = e0 * inv;
    r.y = e1 * inv;
    *(float2*)(out + 2 * b) = r;
}

extern "C" void kernel_launch(void* const* d_in, const int* in_sizes, int n_in,
                              void* d_out, int out_size, void* d_ws, size_t ws_size,
                              hipStream_t stream) {
    const float* x      = (const float*)d_in[0];
    const float* head_w = (const float*)d_in[1];
    const float* head_b = (const float*)d_in[2];
    const float* foot_w = (const float*)d_in[3];
    const float* foot_b = (const float*)d_in[4];
    float* out    = (float*)d_out;
    float* head_t = (float*)d_ws;   // NNEUR*BATCH*4 = 2 MiB scratch, [N][B]

    // kernel 1: NNEUR*BATCH = 524288 rows, 8 rows/wave, 4 waves/block
    const int grid1 = (NNEUR * BATCH) / (8 * 4);   // 16384 blocks
    head_kernel<<<grid1, 256, 0, stream>>>(x, head_w, head_b, head_t);

    // kernel 2: one thread per batch row, 64 threads/block
    foot_kernel<<<BATCH / 64, 64, 0, stream>>>(head_t, foot_w, foot_b, out);
}